// Round 7
// baseline (748.787 us; speedup 1.0000x reference)
//
#include <hip/hip_runtime.h>
#include <hip/hip_bf16.h>
#include <math.h>

#define N 320
#define NN (N * N)          // 102400

typedef float f32x16 __attribute__((ext_vector_type(16)));
typedef short s16x8  __attribute__((ext_vector_type(8)));
typedef unsigned int u32;

#define MFMA32(a, b, c) __builtin_amdgcn_mfma_f32_32x32x16_bf16((a), (b), (c), 0, 0, 0)

union U4V { uint4 q; s16x8 v; };
union UAV { unsigned u[4]; s16x8 v; };

// truncation split: x = hi + lo with hi,lo bf16 (round-toward-zero; rel err ~2^-16 combined)
__device__ inline void split2(float x0, float x1, unsigned& hi, unsigned& lo) {
    unsigned u0 = __float_as_uint(x0), u1 = __float_as_uint(x1);
    hi = (u0 >> 16) | (u1 & 0xFFFF0000u);
    float d0 = x0 - __uint_as_float(u0 & 0xFFFF0000u);
    float d1 = x1 - __uint_as_float(u1 & 0xFFFF0000u);
    lo = (__float_as_uint(d0) >> 16) | (__float_as_uint(d1) & 0xFFFF0000u);
}

// ---------------- fused prep ----------------
// block roles:
//   [  0,100) zero wbuf
//   [100,102) colsum[e] = sum_t s[t][e]; also zero done[e]
//   [102,152) pack s^T   (4 sub-blocks of 64 lanes per block)
//   [152,202) pack W^T
__global__ __launch_bounds__(256) void prep_kernel(
    const float* __restrict__ s, const float* __restrict__ W,
    float* __restrict__ wbuf, float* __restrict__ colsum, unsigned* __restrict__ done,
    uint4* __restrict__ spH, uint4* __restrict__ spL,
    uint4* __restrict__ wpH, uint4* __restrict__ wpL)
{
    const int bid = blockIdx.x;
    const int tid = threadIdx.x;
    if (bid < 100) {
        ((float4*)wbuf)[bid * 256 + tid] = make_float4(0.f, 0.f, 0.f, 0.f);
    } else if (bid < 102) {
        int e = (bid - 100) * 256 + tid;
        if (e < N) {
            done[e] = 0u;
            const float* sp = s + e;
            float a[8];
#pragma unroll
            for (int u = 0; u < 8; ++u) a[u] = 0.f;
            for (int t = 0; t < N; t += 8) {
#pragma unroll
                for (int u = 0; u < 8; ++u) a[u] += sp[(size_t)(t + u) * N];
            }
            colsum[e] = ((a[0] + a[1]) + (a[2] + a[3])) + ((a[4] + a[5]) + (a[6] + a[7]));
        }
    } else if (bid < 152) {
        int sub = (bid - 102) * 4 + (tid >> 6);     // 0..199 = et*20 + ts
        int l = tid & 63;
        int et = sub / 20, ts = sub % 20;
        int e = et * 32 + (l & 31);
        int t0 = ts * 16 + (l >> 5) * 8;
        unsigned hi[4], lo[4];
#pragma unroll
        for (int d = 0; d < 4; ++d)
            split2(s[(size_t)(t0 + 2 * d) * N + e], s[(size_t)(t0 + 2 * d + 1) * N + e],
                   hi[d], lo[d]);
        spH[sub * 64 + l] = make_uint4(hi[0], hi[1], hi[2], hi[3]);
        spL[sub * 64 + l] = make_uint4(lo[0], lo[1], lo[2], lo[3]);
    } else {
        int sub = (bid - 152) * 4 + (tid >> 6);     // 0..199 = jt*20 + ks
        int l = tid & 63;
        int jt = sub / 20, ks = sub % 20;
        int j = jt * 32 + (l & 31);
        int k0 = ks * 16 + (l >> 5) * 8;
        const float* wr = W + (size_t)j * N + k0;
        unsigned hi[4], lo[4];
#pragma unroll
        for (int d = 0; d < 4; ++d) split2(wr[2 * d], wr[2 * d + 1], hi[d], lo[d]);
        wpH[sub * 64 + l] = make_uint4(hi[0], hi[1], hi[2], hi[3]);
        wpL[sub * 64 + l] = make_uint4(lo[0], lo[1], lo[2], lo[3]);
    }
}

// ---------------- fused64: per (i, e-quarter 64), 1600 blocks ----------------
// bid decode: x = bid&7 (XCD), g = bid>>3; iw = g/5, eq = g%5; i = iw*8 + x.
// Phase A: F K-tiles (16x320 f32 = 20480 B, fully contiguous) are double-buffer
// staged into LDS via global_load_lds width-16 (T3-minimum: stage issued after
// the barrier, consumed after the next). ds_read bank = l31 -> conflict-free.
// 4 independent MFMA chains. Phase B: one pass, 4 chains. Softmax via S overlay.
// Tail: per-i done counter; the 5th block computes out[i][:] (fused out-GEMM).
__global__ __launch_bounds__(640, 4) void fused64_kernel(
    const float* __restrict__ fut, const float* __restrict__ s,
    const uint4* __restrict__ spH, const uint4* __restrict__ spL,
    const uint4* __restrict__ wpH, const uint4* __restrict__ wpL,
    const float* __restrict__ bvec, const float* __restrict__ colsum,
    float* __restrict__ w, float* __restrict__ out, unsigned* __restrict__ done)
{
    extern __shared__ char smraw[];
    unsigned short* Gsh = (unsigned short*)smraw;
    float* Ssh = (float*)smraw;
    __shared__ unsigned lastflag;

    const int bid = blockIdx.x;
    const int x  = bid & 7;
    const int g  = bid >> 3;
    const int iw = g / 5, eq = g % 5;
    const int i  = iw * 8 + x;
    const int tid = threadIdx.x;
    const int wid = tid >> 6;         // wave 0..9 = 32-wide j column tile
    const int lane = tid & 63;
    const int l31 = lane & 31;
    const int hf  = lane >> 5;

    // ---------------- phase A: G[2 slabs] = s^T @ F_i, LDS-staged F ----------------
    float* fb0 = (float*)smraw;            // staging buffer 0 (20480 B)
    float* fb1 = (float*)(smraw + 20480);  // staging buffer 1

    // stage K-tile ts into buf: 20480 contiguous bytes; per wave 2 x 1024 B rounds,
    // LDS dest = wave-uniform base (+ lane*16 by HW), global src per-lane.
    auto stageF = [&](int ts, float* buf) {
        const float* src = fut + (size_t)i * NN + (size_t)ts * (16 * N);
#pragma unroll
        for (int r = 0; r < 2; ++r) {
            const float* gp = src + r * 2560 + wid * 256 + lane * 4;
            float* lp = buf + r * 2560 + wid * 256;
            __builtin_amdgcn_global_load_lds(
                (const u32 __attribute__((address_space(1)))*)gp,
                (u32 __attribute__((address_space(3)))*)lp, 16, 0, 0);
        }
    };

    f32x16 c0, c1, c2, c3;
#pragma unroll
    for (int r = 0; r < 16; ++r) { c0[r] = 0.f; c1[r] = 0.f; c2[r] = 0.f; c3[r] = 0.f; }

    const uint4* aH0 = spH + (size_t)((eq * 2 + 0) * 20) * 64 + lane;
    const uint4* aL0 = spL + (size_t)((eq * 2 + 0) * 20) * 64 + lane;
    const uint4* aH1 = spH + (size_t)((eq * 2 + 1) * 20) * 64 + lane;
    const uint4* aL1 = spL + (size_t)((eq * 2 + 1) * 20) * 64 + lane;

    stageF(0, fb0);
    __syncthreads();            // stage(0) drained (vmcnt0) + all waves ready
    stageF(1, fb1);

    for (int ts = 0; ts < 20; ++ts) {
        const float* cb = (ts & 1) ? fb1 : fb0;
        float f[8];
#pragma unroll
        for (int m = 0; m < 8; ++m) f[m] = cb[(hf * 8 + m) * 320 + wid * 32 + l31];
        UAV bh, bl;
#pragma unroll
        for (int d = 0; d < 4; ++d) split2(f[2 * d], f[2 * d + 1], bh.u[d], bl.u[d]);
        U4V a0h, a0l, a1h, a1l;
        a0h.q = aH0[ts * 64]; a0l.q = aL0[ts * 64];
        a1h.q = aH1[ts * 64]; a1l.q = aL1[ts * 64];
        c0 = MFMA32(a0h.v, bh.v, c0);
        c1 = MFMA32(a1h.v, bh.v, c1);
        c2 = MFMA32(a0l.v, bh.v, c2);
        c3 = MFMA32(a1l.v, bh.v, c3);
        c2 = MFMA32(a0h.v, bl.v, c2);
        c3 = MFMA32(a1h.v, bl.v, c3);
        __syncthreads();        // drains my ds reads + stage(ts+1) writes
        if (ts + 2 < 20) stageF(ts + 2, (ts & 1) ? fb1 : fb0);
    }
    // last barrier (end ts=19): all waves done reading staging buffers.

    // G -> LDS bf16 hi/lo in frag-linear swizzled layout (both slabs)
    {
        unsigned short* GH0 = Gsh;
        unsigned short* GL0 = Gsh + 10240;
        unsigned short* GH1 = Gsh + 20480;
        unsigned short* GL1 = Gsh + 30720;
        const int c  = wid * 4 + (l31 >> 3);
        const int jj = l31 & 7;
        const int sw = c & 7;
#pragma unroll
        for (int r = 0; r < 16; ++r) {
            int e = (r & 3) + ((r >> 2) << 3) + (hf << 2);
            int off = (c * 32 + (e ^ sw)) * 8 + jj;
            {
                float xv = c0[r] + c2[r];
                unsigned u = __float_as_uint(xv);
                float d = xv - __uint_as_float(u & 0xFFFF0000u);
                GH0[off] = (unsigned short)(u >> 16);
                GL0[off] = (unsigned short)(__float_as_uint(d) >> 16);
            }
            {
                float xv = c1[r] + c3[r];
                unsigned u = __float_as_uint(xv);
                float d = xv - __uint_as_float(u & 0xFFFF0000u);
                GH1[off] = (unsigned short)(u >> 16);
                GL1[off] = (unsigned short)(__float_as_uint(d) >> 16);
            }
        }
    }
    __syncthreads();   // B1: G visible

    // ---------------- phase B: S = G @ W^T (+ colsum*b), one pass -------
    f32x16 p0a, p0b, p1a, p1b;
#pragma unroll
    for (int r = 0; r < 16; ++r) { p0a[r] = 0.f; p0b[r] = 0.f; p1a[r] = 0.f; p1b[r] = 0.f; }

    const uint4* bHp = wpH + (size_t)(wid * 20) * 64 + lane;
    const uint4* bLp = wpL + (size_t)(wid * 20) * 64 + lane;
    const unsigned short* GH0 = Gsh;
    const unsigned short* GL0 = Gsh + 10240;
    const unsigned short* GH1 = Gsh + 20480;
    const unsigned short* GL1 = Gsh + 30720;

#pragma unroll 2
    for (int ks = 0; ks < 20; ++ks) {
        int c = ks * 2 + hf;
        int off = (c * 32 + (l31 ^ (c & 7))) * 8;
        s16x8 gh0 = *(const s16x8*)&GH0[off];
        s16x8 gl0 = *(const s16x8*)&GL0[off];
        s16x8 gh1 = *(const s16x8*)&GH1[off];
        s16x8 gl1 = *(const s16x8*)&GL1[off];
        U4V wh, wl;
        wh.q = bHp[ks * 64];
        wl.q = bLp[ks * 64];
        p0a = MFMA32(gh0, wh.v, p0a);
        p1a = MFMA32(gh1, wh.v, p1a);
        p0b = MFMA32(gl0, wh.v, p0b);
        p1b = MFMA32(gl1, wh.v, p1b);
        p0b = MFMA32(gh0, wl.v, p0b);
        p1b = MFMA32(gh1, wl.v, p1b);
    }

    const int jcol = wid * 32 + l31;
    const float bj = bvec[jcol];
    float v0[16], v1[16];
#pragma unroll
    for (int r = 0; r < 16; ++r) {
        int e = (r & 3) + ((r >> 2) << 3) + (hf << 2);
        v0[r] = (p0a[r] + p0b[r]) + colsum[eq * 64 + e] * bj;
        v1[r] = (p1a[r] + p1b[r]) + colsum[eq * 64 + 32 + e] * bj;
    }
    __syncthreads();   // B2: all G reads done before S overlays G

#pragma unroll
    for (int r = 0; r < 16; ++r) {
        int e = (r & 3) + ((r >> 2) << 3) + (hf << 2);
        Ssh[e * 320 + jcol] = v0[r];
        Ssh[(32 + e) * 320 + jcol] = v1[r];
    }
    __syncthreads();   // B3

    // row sweeps: half-wave hw (0..19) handles rows q*20+hw (<64).
    const int hw = tid >> 5;
    const int li = tid & 31;
#pragma unroll
    for (int q = 0; q < 4; ++q) {
        int row = q * 20 + hw;
        if (row < 64) {
            float xr[10];
            float m = -3.4e38f;
#pragma unroll
            for (int k = 0; k < 10; ++k) {
                xr[k] = Ssh[row * 320 + li + 32 * k];
                m = fmaxf(m, xr[k]);
            }
#pragma unroll
            for (int off = 16; off; off >>= 1) m = fmaxf(m, __shfl_xor(m, off, 64));
            float ss = 0.f;
#pragma unroll
            for (int k = 0; k < 10; ++k) ss += __expf(xr[k] - m);
#pragma unroll
            for (int off = 16; off; off >>= 1) ss += __shfl_xor(ss, off, 64);
            if (li == 0) { Ssh[row * 320 + 0] = m; Ssh[row * 320 + 1] = 1.0f / ss; }
        }
    }
    __syncthreads();   // B4

    float wcol = 0.f;
#pragma unroll
    for (int r = 0; r < 16; ++r) {
        int e = (r & 3) + ((r >> 2) << 3) + (hf << 2);
        wcol += __expf(v0[r] - Ssh[e * 320]) * Ssh[e * 320 + 1];
        wcol += __expf(v1[r] - Ssh[(32 + e) * 320]) * Ssh[(32 + e) * 320 + 1];
    }
    wcol += __shfl_xor(wcol, 32, 64);
    if (hf == 0) atomicAdd(&w[(size_t)i * N + jcol], wcol);

    // ---------------- fused out-GEMM tail: last of the 5 blocks of i ----------------
    __threadfence();                   // release this block's w atomics (device scope)
    __syncthreads();
    if (tid == 0) lastflag = (atomicAdd(&done[i], 1u) == 4u) ? 1u : 0u;
    __syncthreads();
    if (lastflag) {
        float* wrow = Ssh;             // 320 f32 scratch (S dead now)
        if (tid < N) wrow[tid] = atomicAdd(&w[(size_t)i * N + tid], 0.0f);  // L2-coherent read
        __syncthreads();
        if (tid < N) {
            const int k = tid;
            const float* sp = s + k;
            float a0 = 0.f, a1 = 0.f, a2 = 0.f, a3 = 0.f;
            for (int j = 0; j < N; j += 4) {
                a0 += wrow[j + 0] * sp[(size_t)(j + 0) * N];
                a1 += wrow[j + 1] * sp[(size_t)(j + 1) * N];
                a2 += wrow[j + 2] * sp[(size_t)(j + 2) * N];
                a3 += wrow[j + 3] * sp[(size_t)(j + 3) * N];
            }
            out[(size_t)i * N + k] = (a0 + a1) + (a2 + a3);
        }
    }
}

extern "C" void kernel_launch(void* const* d_in, const int* in_sizes, int n_in,
                              void* d_out, int out_size, void* d_ws, size_t ws_size,
                              hipStream_t stream)
{
    const float* s    = (const float*)d_in[0];
    const float* fut  = (const float*)d_in[1];
    const float* W    = (const float*)d_in[2];
    const float* bvec = (const float*)d_in[3];
    float* out = (float*)d_out;

    char* base = (char*)d_ws;
    float* wbuf     = (float*)base;                      // 409600 B
    float* colsum   = (float*)(base + 409600);           // 1280 B
    unsigned* done  = (unsigned*)(base + 410880);        // 1280 B
    uint4* spH = (uint4*)(base + 412160);                // 204800 B
    uint4* spL = (uint4*)(base + 616960);                // 204800 B
    uint4* wpH = (uint4*)(base + 821760);                // 204800 B
    uint4* wpL = (uint4*)(base + 1026560);               // 204800 B

    static bool attr_done = false;
    if (!attr_done) {
        (void)hipFuncSetAttribute((const void*)fused64_kernel,
                                  hipFuncAttributeMaxDynamicSharedMemorySize, 81920);
        attr_done = true;
    }

    prep_kernel<<<dim3(202), dim3(256), 0, stream>>>(
        s, W, wbuf, colsum, done, spH, spL, wpH, wpL);

    fused64_kernel<<<dim3(1600), dim3(640), 81920, stream>>>(
        fut, s, spH, spL, wpH, wpL, bvec, colsum, wbuf, out, done);
}